// Round 19
// baseline (158.430 us; speedup 1.0000x reference)
//
#include <hip/hip_runtime.h>
#include <stdint.h>

typedef unsigned short u16;
typedef unsigned int u32;
typedef __bf16 bf16x8 __attribute__((ext_vector_type(8)));
typedef float f32x4 __attribute__((ext_vector_type(4)));

// ---------- helpers ----------
__device__ __forceinline__ float bf2f(u16 u) {
  return __builtin_bit_cast(float, (u32)u << 16);
}
__device__ __forceinline__ u16 f2b(float f) {
  u32 u = __builtin_bit_cast(u32, f);
  u32 r = (u + 0x7fffu + ((u >> 16) & 1u)) >> 16;  // RNE
  return (u16)r;
}
__device__ __forceinline__ void gload16(const u16* g, u16* l) {
  __builtin_amdgcn_global_load_lds(
      (const __attribute__((address_space(1))) u32*)(const void*)g,
      (__attribute__((address_space(3))) u32*)(void*)l, 16, 0, 0);
}

// ---------- fp32 -> bf16 convert: x, W_qkv, W_out in ONE launch ----------
__global__ __launch_bounds__(256) void cvt3(
    const float* __restrict__ a, u16* __restrict__ ao, int na4,
    const float* __restrict__ b, u16* __restrict__ bo, int nb4,
    const float* __restrict__ c, u16* __restrict__ co, int nc4) {
  const int total = na4 + nb4 + nc4;
  for (int i = blockIdx.x * 256 + threadIdx.x; i < total; i += gridDim.x * 256) {
    const float4* src;
    ushort4* dst;
    int idx;
    if (i < na4) {
      src = reinterpret_cast<const float4*>(a); dst = reinterpret_cast<ushort4*>(ao); idx = i;
    } else if (i < na4 + nb4) {
      src = reinterpret_cast<const float4*>(b); dst = reinterpret_cast<ushort4*>(bo); idx = i - na4;
    } else {
      src = reinterpret_cast<const float4*>(c); dst = reinterpret_cast<ushort4*>(co); idx = i - na4 - nb4;
    }
    float4 v = src[idx];
    ushort4 o;
    o.x = f2b(v.x); o.y = f2b(v.y); o.z = f2b(v.z); o.w = f2b(v.w);
    dst[idx] = o;
  }
}

// ---------- bf16 GEMM  C[M,N] = A[M,K] * B[N,K]^T ----------
// 128x128 tile, BK=32, 4 waves (2x2), 16x16x32 MFMA.
// TB=3 (gemm1, grid 1536 = 2.0 rounds @3/CU): triple-buffered LDS, ONE
//   barrier per K-tile, counted vmcnt(4) — stage(t) waited 2 compute bodies
//   after issue; stage(t+2) overwrites buf[(t-1)%3] only after barrier(t).
// TB=2 (gemm2, grid 1024 = 1.0 round @4/CU): double-buffer, stage(t+1)
//   at iter top, one __syncthreads (implicit vmcnt0) per tile.
// LDS swizzle (r9-verified zero-conflict): 16B-slot s -> s ^ ((row>>1)&3),
// pre-swizzled global source (linear global_load_lds dest) + same XOR on
// ds_read. A row stride = lda (gemm2 reads q-section of qkv in place).
// MODE 0: bf16 out + fused per-head LN. MODE 1: fp32 out + bias, B per-batch.
template <int MODE, int TB>
__global__ __launch_bounds__(256, (TB == 3) ? 3 : 4) void gemm_bt(
    const u16* __restrict__ A, const u16* __restrict__ B, void* __restrict__ C,
    const float* __restrict__ gq, const float* __restrict__ bq,
    const float* __restrict__ gk, const float* __restrict__ bk,
    const float* __restrict__ bias, int M, int N, int K, int ntn,
    int lda, size_t bstride) {
  __shared__ u16 As[TB][128 * 32];
  __shared__ u16 Bs[TB][128 * 32];

  // XCD-aware bijective swizzle (grid % 8 == 0 at both call sites)
  const int nwg = gridDim.x;
  const int bid0 = blockIdx.x;
  const int bid = (bid0 & 7) * (nwg >> 3) + (bid0 >> 3);
  const int tm = bid / ntn, tn = bid % ntn;
  const int brow = tm << 7, bcol = tn << 7;
  const int tid = threadIdx.x;
  const int w = tid >> 6, lane = tid & 63;
  const int wrow = (w >> 1) << 6, wcol = (w & 1) << 6;
  const int lr = lane & 15, lg = lane >> 4;

  const u16* Bp = (MODE == 1) ? (B + (size_t)(brow >> 12) * bstride) : B;

  // staging: lane covers (row = 16g + lane/4, slot = lane&3); global source
  // slot pre-swizzled: (lane&3) ^ ((row>>1)&3), row>>1 bits = lane>>3.
  const int sslot = (lane & 3) ^ ((lane >> 3) & 3);
  const u16* Asrc = A + (size_t)(brow + (lane >> 2)) * lda + sslot * 8;
  const u16* Bsrc = Bp + (size_t)(bcol + (lane >> 2)) * K + sslot * 8;

  auto stage = [&](int t, int buf) {
    const int k0 = t << 5;
#pragma unroll
    for (int i = 0; i < 2; ++i) {
      int g = w + 4 * i;  // wave-uniform row-group (16 rows, 1 KiB)
      gload16(Asrc + (size_t)(16 * g) * lda + k0, &As[buf][(16 * g) * 32]);
      gload16(Bsrc + (size_t)(16 * g) * K + k0, &Bs[buf][(16 * g) * 32]);
    }
  };

  f32x4 acc[4][4];
#pragma unroll
  for (int m = 0; m < 4; ++m)
#pragma unroll
    for (int n = 0; n < 4; ++n) acc[m][n] = (f32x4){0.f, 0.f, 0.f, 0.f};

  const int NC = K >> 5;
  // swizzled ds_read 16B-slot (elems): lg ^ ((row>>1)&3), row>>1 bits = lr>>1
  const int kslot = (lg ^ ((lr >> 1) & 3)) << 3;

  auto compute = [&](const u16* Asb, const u16* Bsb) {
    bf16x8 af[4], bfr[4];
#pragma unroll
    for (int m = 0; m < 4; ++m)
      af[m] = *reinterpret_cast<const bf16x8*>(&Asb[(wrow + m * 16 + lr) * 32 + kslot]);
#pragma unroll
    for (int n = 0; n < 4; ++n)
      bfr[n] = *reinterpret_cast<const bf16x8*>(&Bsb[(wcol + n * 16 + lr) * 32 + kslot]);
    __builtin_amdgcn_s_setprio(1);
#pragma unroll
    for (int m = 0; m < 4; ++m)
#pragma unroll
      for (int n = 0; n < 4; ++n)
        acc[m][n] = __builtin_amdgcn_mfma_f32_16x16x32_bf16(af[m], bfr[n], acc[m][n], 0, 0, 0);
    __builtin_amdgcn_s_setprio(0);
  };

  if constexpr (TB == 3) {
    stage(0, 0);
    stage(1, 1);
    int cur = 0, nx2 = 2;  // cur = t%3, nx2 = (t+2)%3
    for (int t = 0; t < NC; ++t) {
      if (t + 1 < NC)
        asm volatile("s_waitcnt vmcnt(4)" ::: "memory");
      else
        asm volatile("s_waitcnt vmcnt(0)" ::: "memory");
      __builtin_amdgcn_s_barrier();
      asm volatile("" ::: "memory");
      if (t + 2 < NC) stage(t + 2, nx2);
      compute(As[cur], Bs[cur]);
      asm volatile("" ::: "memory");
      cur = (cur == 2) ? 0 : cur + 1;
      nx2 = (nx2 == 2) ? 0 : nx2 + 1;
    }
  } else {
    stage(0, 0);
    __syncthreads();
    for (int t = 0; t < NC; ++t) {
      const int cur = t & 1;
      if (t + 1 < NC) stage(t + 1, cur ^ 1);
      compute(As[cur], Bs[cur]);
      __syncthreads();  // implicit vmcnt(0): drains stage(t+1), full-tile cover
    }
  }

  // C/D layout: col = lane&15, row = (lane>>4)*4 + reg
  const int orow = brow + wrow + ((lane >> 4) << 2);
  const int ocol = bcol + wcol + lr;
  if (MODE == 0) {
    const int wcol0 = bcol + wcol;  // 64-aligned -> exactly one head slice
    const int sect = wcol0 >> 6;    // 0..7 q, 8..15 k, 16..23 v
    const bool doln = sect < 16;
    const float* Gp = (sect < 8) ? (gq + wcol0) : (gk + (wcol0 - 512));
    const float* Pp = (sect < 8) ? (bq + wcol0) : (bk + (wcol0 - 512));
    float gv[4], pv[4];
    if (doln) {
#pragma unroll
      for (int n = 0; n < 4; ++n) { gv[n] = Gp[n * 16 + lr]; pv[n] = Pp[n * 16 + lr]; }
    }
    u16* Cp = (u16*)C;
#pragma unroll
    for (int m = 0; m < 4; ++m)
#pragma unroll
      for (int r = 0; r < 4; ++r) {
        size_t rowoff = (size_t)(orow + m * 16 + r) * N;
        if (doln) {
          float s = 0.f, s2 = 0.f;
#pragma unroll
          for (int n = 0; n < 4; ++n) {
            float x = acc[m][n][r];
            s += x; s2 += x * x;
          }
#pragma unroll
          for (int off = 8; off; off >>= 1) {
            s += __shfl_xor(s, off, 64);
            s2 += __shfl_xor(s2, off, 64);
          }
          float mean = s * 0.015625f;
          float inv = rsqrtf(s2 * 0.015625f - mean * mean + 1e-5f);
#pragma unroll
          for (int n = 0; n < 4; ++n)
            Cp[rowoff + ocol + n * 16] =
                f2b((acc[m][n][r] - mean) * inv * gv[n] + pv[n]);
        } else {
#pragma unroll
          for (int n = 0; n < 4; ++n)
            Cp[rowoff + ocol + n * 16] = f2b(acc[m][n][r]);
        }
      }
  } else {
    float bvv[4];
#pragma unroll
    for (int n = 0; n < 4; ++n) bvv[n] = bias[ocol + n * 16];
    float* Cp = (float*)C;
#pragma unroll
    for (int m = 0; m < 4; ++m)
#pragma unroll
      for (int r = 0; r < 4; ++r) {
        size_t rowoff = (size_t)(orow + m * 16 + r) * N;
#pragma unroll
        for (int n = 0; n < 4; ++n)
          Cp[rowoff + ocol + n * 16] = acc[m][n][r] + bvv[n];
      }
  }
}

// ---------- KVpart[bh][nch] = sum_{n in chunk} k[n,d]*v[n,e] (NO atomics) ----------
// bf16 LDS staging (raw copy, no fp32 unpack) with +8 row pad ([64][72],
// 144B stride): write bank-starts spread (4g+8c)%32 -> ~8-way (was 32-way
// with the fp32 [64][64] layout); halves LDS bytes. Inner loop converts
// 8 bf16/n via shifts (bit-identical math to the fp32-staged version).
__global__ __launch_bounds__(256) void kv_accum(const u16* __restrict__ qkv,
                                                float* __restrict__ KVpart) {
  int nch = blockIdx.x & 15;  // 16 chunks of 256 rows
  int bh = blockIdx.x >> 4;   // 0..31
  int b = bh >> 3, h = bh & 7;
  __shared__ u16 ks[64][72];
  __shared__ u16 vs[64][72];
  int tid = threadIdx.x;
  int ty = tid >> 4, tx = tid & 15;
  int rr = tid >> 2, cc = (tid & 3) * 16;
  float acc[4][4];
#pragma unroll
  for (int i = 0; i < 4; ++i)
#pragma unroll
    for (int j = 0; j < 4; ++j) acc[i][j] = 0.f;

  for (int t = 0; t < 4; ++t) {
    int n0 = nch * 256 + t * 64;
    __syncthreads();
    size_t base = ((size_t)(b * 4096 + n0 + rr)) * 1536 + h * 64 + cc;
    const uint4* kp = reinterpret_cast<const uint4*>(&qkv[base + 512]);
    const uint4* vp = reinterpret_cast<const uint4*>(&qkv[base + 1024]);
    uint4 k0 = kp[0], k1 = kp[1];
    uint4 v0 = vp[0], v1 = vp[1];
    *reinterpret_cast<uint4*>(&ks[rr][cc])     = k0;
    *reinterpret_cast<uint4*>(&ks[rr][cc + 8]) = k1;
    *reinterpret_cast<uint4*>(&vs[rr][cc])     = v0;
    *reinterpret_cast<uint4*>(&vs[rr][cc + 8]) = v1;
    __syncthreads();
    for (int n = 0; n < 64; ++n) {
      ushort4 k4 = *reinterpret_cast<const ushort4*>(&ks[n][ty * 4]);
      ushort4 v4 = *reinterpret_cast<const ushort4*>(&vs[n][tx * 4]);
      float ka[4] = {bf2f(k4.x), bf2f(k4.y), bf2f(k4.z), bf2f(k4.w)};
      float va[4] = {bf2f(v4.x), bf2f(v4.y), bf2f(v4.z), bf2f(v4.w)};
#pragma unroll
      for (int i = 0; i < 4; ++i)
#pragma unroll
        for (int j = 0; j < 4; ++j) acc[i][j] += ka[i] * va[j];
    }
  }
  float* dst = KVpart + ((size_t)(bh * 16 + nch)) * 4096;
#pragma unroll
  for (int i = 0; i < 4; ++i) {
    float4 st = {acc[i][0], acc[i][1], acc[i][2], acc[i][3]};
    *reinterpret_cast<float4*>(&dst[(ty * 4 + i) * 64 + tx * 4]) = st;
  }
}

// ---------- KV[bh] = sum over 16 partials ----------
__global__ __launch_bounds__(256) void kv_reduce(const float* __restrict__ KVpart,
                                                 float* __restrict__ KV) {
  int bh = blockIdx.x;  // 32
  int t = threadIdx.x;
  const float4* src = reinterpret_cast<const float4*>(KVpart + (size_t)bh * 16 * 4096);
  float4* dst = reinterpret_cast<float4*>(KV + (size_t)bh * 4096);
#pragma unroll
  for (int i = 0; i < 4; ++i) {
    int idx = t + 256 * i;
    float4 s = src[idx];
#pragma unroll
    for (int c = 1; c < 16; ++c) {
      float4 v = src[c * 1024 + idx];
      s.x += v.x; s.y += v.y; s.z += v.z; s.w += v.w;
    }
    dst[idx] = s;
  }
}

// ---------- W2[b][j][h*64+d] = scale * sum_e KV[b,h,d,e] * Wo[j,h*64+e] ----------
__global__ __launch_bounds__(256) void w2_kernel(const float* __restrict__ KV,
                                                 const u16* __restrict__ wob,
                                                 u16* __restrict__ w2) {
  int bh = blockIdx.x & 31, jt = blockIdx.x >> 5;  // jt 0..7
  int b = bh >> 3, h = bh & 7;
  __shared__ float kvs[64][64];
  int t = threadIdx.x;
  {
    const float4* src = reinterpret_cast<const float4*>(KV + (size_t)bh * 4096);
    float4* dst = reinterpret_cast<float4*>(&kvs[0][0]);
#pragma unroll
    for (int i = 0; i < 4; ++i) dst[t + 256 * i] = src[t + 256 * i];
  }
  __syncthreads();
  int jloc = t & 127, dg = t >> 7;
  int j = jt * 128 + jloc;
  float wo[64];
  const u16* wr = wob + (size_t)j * 512 + h * 64;
#pragma unroll
  for (int e8 = 0; e8 < 8; ++e8) {
    uint4 pk = *reinterpret_cast<const uint4*>(wr + e8 * 8);
    u32 wds[4] = {pk.x, pk.y, pk.z, pk.w};
#pragma unroll
    for (int i = 0; i < 4; ++i) {
      wo[e8 * 8 + 2 * i]     = bf2f((u16)(wds[i] & 0xffffu));
      wo[e8 * 8 + 2 * i + 1] = bf2f((u16)(wds[i] >> 16));
    }
  }
  const float scale = 1.0f / 32768.0f;  // 1/(sqrt(64)*4096)
  u16* outp = w2 + ((size_t)b * 1024 + j) * 512 + h * 64 + dg * 32;
#pragma unroll
  for (int dd = 0; dd < 32; ++dd) {
    int d = dg * 32 + dd;
    float acc = 0.f;
    const float4* kr = reinterpret_cast<const float4*>(&kvs[d][0]);
#pragma unroll
    for (int e4 = 0; e4 < 16; ++e4) {
      float4 kv4 = kr[e4];
      acc += kv4.x * wo[e4 * 4] + kv4.y * wo[e4 * 4 + 1] +
             kv4.z * wo[e4 * 4 + 2] + kv4.w * wo[e4 * 4 + 3];
    }
    outp[dd] = f2b(acc * scale);
  }
}

// ---------- launch ----------
extern "C" void kernel_launch(void* const* d_in, const int* in_sizes, int n_in,
                              void* d_out, int out_size, void* d_ws, size_t ws_size,
                              hipStream_t stream) {
  const float* x  = (const float*)d_in[0];
  const float* Wq = (const float*)d_in[1];
  const float* gq = (const float*)d_in[2];
  const float* bq = (const float*)d_in[3];
  const float* gk = (const float*)d_in[4];
  const float* bk = (const float*)d_in[5];
  const float* Wo = (const float*)d_in[6];
  const float* bo = (const float*)d_in[7];
  float* out = (float*)d_out;

  char* p = (char*)d_ws;
  auto carve = [&](size_t bytes) {
    char* r = p;
    p += (bytes + 255) & ~(size_t)255;
    return r;
  };
  u16* xb      = (u16*)carve((size_t)16384 * 1024 * 2);
  u16* wqb     = (u16*)carve((size_t)1536 * 1024 * 2);
  u16* wob     = (u16*)carve((size_t)1024 * 512 * 2);
  u16* qkv     = (u16*)carve((size_t)16384 * 1536 * 2);
  float* KVp   = (float*)carve((size_t)32 * 16 * 4096 * 4);
  float* KVb   = (float*)carve((size_t)32 * 4096 * 4);
  u16* w2b     = (u16*)carve((size_t)4 * 1024 * 512 * 2);

  // one launch converts x, W_qkv, W_out to bf16
  cvt3<<<2048, 256, 0, stream>>>(x, xb, 4194304, Wq, wqb, 393216, Wo, wob, 131072);
  // qkv = x @ Wqkv^T  [16384,1536], fused per-head LN on q,k  (3-buffer)
  gemm_bt<0, 3><<<128 * 12, 256, 0, stream>>>(xb, wqb, qkv, gq, bq, gk, bk,
                                              nullptr, 16384, 1536, 1024, 12,
                                              1024, 0);
  // KV partials (no atomics, bf16 padded LDS) then reduce
  kv_accum<<<512, 256, 0, stream>>>(qkv, KVp);
  kv_reduce<<<32, 256, 0, stream>>>(KVp, KVb);
  // W2[b] = scale * KV[b] @ Wo-slices
  w2_kernel<<<256, 256, 0, stream>>>(KVb, wob, w2b);
  // out = q @ W2[b]^T + b_out  [16384,1024] fp32  (2-buffer, 4 blk/CU, 1 round)
  gemm_bt<1, 2><<<128 * 8, 256, 0, stream>>>(qkv, w2b, out, nullptr, nullptr,
                                             nullptr, nullptr, bo, 16384, 1024,
                                             512, 8, 1536, (size_t)1024 * 512);
}

// Round 20
// 155.205 us; speedup vs baseline: 1.0208x; 1.0208x over previous
//
#include <hip/hip_runtime.h>
#include <stdint.h>

typedef unsigned short u16;
typedef unsigned int u32;
typedef __bf16 bf16x8 __attribute__((ext_vector_type(8)));
typedef float f32x4 __attribute__((ext_vector_type(4)));

// ---------- helpers ----------
__device__ __forceinline__ float bf2f(u16 u) {
  return __builtin_bit_cast(float, (u32)u << 16);
}
__device__ __forceinline__ u16 f2b(float f) {
  u32 u = __builtin_bit_cast(u32, f);
  u32 r = (u + 0x7fffu + ((u >> 16) & 1u)) >> 16;  // RNE
  return (u16)r;
}
__device__ __forceinline__ void gload16(const u16* g, u16* l) {
  __builtin_amdgcn_global_load_lds(
      (const __attribute__((address_space(1))) u32*)(const void*)g,
      (__attribute__((address_space(3))) u32*)(void*)l, 16, 0, 0);
}
__device__ __forceinline__ void unpack16(uint4 a, uint4 b, float* o) {
  u32 w[8] = {a.x, a.y, a.z, a.w, b.x, b.y, b.z, b.w};
#pragma unroll
  for (int i = 0; i < 8; ++i) {
    o[2 * i]     = __builtin_bit_cast(float, w[i] << 16);
    o[2 * i + 1] = __builtin_bit_cast(float, w[i] & 0xffff0000u);
  }
}

// ---------- fp32 -> bf16 convert: x, W_qkv, W_out in ONE launch ----------
__global__ __launch_bounds__(256) void cvt3(
    const float* __restrict__ a, u16* __restrict__ ao, int na4,
    const float* __restrict__ b, u16* __restrict__ bo, int nb4,
    const float* __restrict__ c, u16* __restrict__ co, int nc4) {
  const int total = na4 + nb4 + nc4;
  for (int i = blockIdx.x * 256 + threadIdx.x; i < total; i += gridDim.x * 256) {
    const float4* src;
    ushort4* dst;
    int idx;
    if (i < na4) {
      src = reinterpret_cast<const float4*>(a); dst = reinterpret_cast<ushort4*>(ao); idx = i;
    } else if (i < na4 + nb4) {
      src = reinterpret_cast<const float4*>(b); dst = reinterpret_cast<ushort4*>(bo); idx = i - na4;
    } else {
      src = reinterpret_cast<const float4*>(c); dst = reinterpret_cast<ushort4*>(co); idx = i - na4 - nb4;
    }
    float4 v = src[idx];
    ushort4 o;
    o.x = f2b(v.x); o.y = f2b(v.y); o.z = f2b(v.z); o.w = f2b(v.w);
    dst[idx] = o;
  }
}

// ---------- bf16 GEMM  C[M,N] = A[M,K] * B[N,K]^T ----------
// 128x128 tile, BK=32, 4 waves (2x2), 16x16x32 MFMA.
// TB=3 (gemm1, grid 1536 = 2.0 rounds @3/CU): triple-buffered LDS, ONE
//   barrier per K-tile, counted vmcnt(4) — stage(t) waited 2 compute bodies
//   after issue; stage(t+2) overwrites buf[(t-1)%3] only after barrier(t).
// TB=2 (gemm2, grid 1024 = 1.0 round @4/CU): double-buffer, stage(t+1)
//   at iter top, one __syncthreads (implicit vmcnt0) per tile.
// LDS swizzle (r9-verified zero-conflict): 16B-slot s -> s ^ ((row>>1)&3),
// pre-swizzled global source (linear global_load_lds dest) + same XOR on
// ds_read. A row stride = lda (gemm2 reads q-section of qkv in place).
// MODE 0: bf16 out + fused per-head LN. MODE 1: fp32 out + bias, B per-batch.
template <int MODE, int TB>
__global__ __launch_bounds__(256, (TB == 3) ? 3 : 4) void gemm_bt(
    const u16* __restrict__ A, const u16* __restrict__ B, void* __restrict__ C,
    const float* __restrict__ gq, const float* __restrict__ bq,
    const float* __restrict__ gk, const float* __restrict__ bk,
    const float* __restrict__ bias, int M, int N, int K, int ntn,
    int lda, size_t bstride) {
  __shared__ u16 As[TB][128 * 32];
  __shared__ u16 Bs[TB][128 * 32];

  // XCD-aware bijective swizzle (grid % 8 == 0 at both call sites)
  const int nwg = gridDim.x;
  const int bid0 = blockIdx.x;
  const int bid = (bid0 & 7) * (nwg >> 3) + (bid0 >> 3);
  const int tm = bid / ntn, tn = bid % ntn;
  const int brow = tm << 7, bcol = tn << 7;
  const int tid = threadIdx.x;
  const int w = tid >> 6, lane = tid & 63;
  const int wrow = (w >> 1) << 6, wcol = (w & 1) << 6;
  const int lr = lane & 15, lg = lane >> 4;

  const u16* Bp = (MODE == 1) ? (B + (size_t)(brow >> 12) * bstride) : B;

  // staging: lane covers (row = 16g + lane/4, slot = lane&3); global source
  // slot pre-swizzled: (lane&3) ^ ((row>>1)&3), row>>1 bits = lane>>3.
  const int sslot = (lane & 3) ^ ((lane >> 3) & 3);
  const u16* Asrc = A + (size_t)(brow + (lane >> 2)) * lda + sslot * 8;
  const u16* Bsrc = Bp + (size_t)(bcol + (lane >> 2)) * K + sslot * 8;

  auto stage = [&](int t, int buf) {
    const int k0 = t << 5;
#pragma unroll
    for (int i = 0; i < 2; ++i) {
      int g = w + 4 * i;  // wave-uniform row-group (16 rows, 1 KiB)
      gload16(Asrc + (size_t)(16 * g) * lda + k0, &As[buf][(16 * g) * 32]);
      gload16(Bsrc + (size_t)(16 * g) * K + k0, &Bs[buf][(16 * g) * 32]);
    }
  };

  f32x4 acc[4][4];
#pragma unroll
  for (int m = 0; m < 4; ++m)
#pragma unroll
    for (int n = 0; n < 4; ++n) acc[m][n] = (f32x4){0.f, 0.f, 0.f, 0.f};

  const int NC = K >> 5;
  // swizzled ds_read 16B-slot (elems): lg ^ ((row>>1)&3), row>>1 bits = lr>>1
  const int kslot = (lg ^ ((lr >> 1) & 3)) << 3;

  auto compute = [&](const u16* Asb, const u16* Bsb) {
    bf16x8 af[4], bfr[4];
#pragma unroll
    for (int m = 0; m < 4; ++m)
      af[m] = *reinterpret_cast<const bf16x8*>(&Asb[(wrow + m * 16 + lr) * 32 + kslot]);
#pragma unroll
    for (int n = 0; n < 4; ++n)
      bfr[n] = *reinterpret_cast<const bf16x8*>(&Bsb[(wcol + n * 16 + lr) * 32 + kslot]);
    __builtin_amdgcn_s_setprio(1);
#pragma unroll
    for (int m = 0; m < 4; ++m)
#pragma unroll
      for (int n = 0; n < 4; ++n)
        acc[m][n] = __builtin_amdgcn_mfma_f32_16x16x32_bf16(af[m], bfr[n], acc[m][n], 0, 0, 0);
    __builtin_amdgcn_s_setprio(0);
  };

  if constexpr (TB == 3) {
    stage(0, 0);
    stage(1, 1);
    int cur = 0, nx2 = 2;  // cur = t%3, nx2 = (t+2)%3
    for (int t = 0; t < NC; ++t) {
      if (t + 1 < NC)
        asm volatile("s_waitcnt vmcnt(4)" ::: "memory");
      else
        asm volatile("s_waitcnt vmcnt(0)" ::: "memory");
      __builtin_amdgcn_s_barrier();
      asm volatile("" ::: "memory");
      if (t + 2 < NC) stage(t + 2, nx2);
      compute(As[cur], Bs[cur]);
      asm volatile("" ::: "memory");
      cur = (cur == 2) ? 0 : cur + 1;
      nx2 = (nx2 == 2) ? 0 : nx2 + 1;
    }
  } else {
    stage(0, 0);
    __syncthreads();
    for (int t = 0; t < NC; ++t) {
      const int cur = t & 1;
      if (t + 1 < NC) stage(t + 1, cur ^ 1);
      compute(As[cur], Bs[cur]);
      __syncthreads();  // implicit vmcnt(0): drains stage(t+1), full-tile cover
    }
  }

  // C/D layout: col = lane&15, row = (lane>>4)*4 + reg
  const int orow = brow + wrow + ((lane >> 4) << 2);
  const int ocol = bcol + wcol + lr;
  if (MODE == 0) {
    const int wcol0 = bcol + wcol;  // 64-aligned -> exactly one head slice
    const int sect = wcol0 >> 6;    // 0..7 q, 8..15 k, 16..23 v
    const bool doln = sect < 16;
    const float* Gp = (sect < 8) ? (gq + wcol0) : (gk + (wcol0 - 512));
    const float* Pp = (sect < 8) ? (bq + wcol0) : (bk + (wcol0 - 512));
    float gv[4], pv[4];
    if (doln) {
#pragma unroll
      for (int n = 0; n < 4; ++n) { gv[n] = Gp[n * 16 + lr]; pv[n] = Pp[n * 16 + lr]; }
    }
    u16* Cp = (u16*)C;
#pragma unroll
    for (int m = 0; m < 4; ++m)
#pragma unroll
      for (int r = 0; r < 4; ++r) {
        size_t rowoff = (size_t)(orow + m * 16 + r) * N;
        if (doln) {
          float s = 0.f, s2 = 0.f;
#pragma unroll
          for (int n = 0; n < 4; ++n) {
            float x = acc[m][n][r];
            s += x; s2 += x * x;
          }
#pragma unroll
          for (int off = 8; off; off >>= 1) {
            s += __shfl_xor(s, off, 64);
            s2 += __shfl_xor(s2, off, 64);
          }
          float mean = s * 0.015625f;
          float inv = rsqrtf(s2 * 0.015625f - mean * mean + 1e-5f);
#pragma unroll
          for (int n = 0; n < 4; ++n)
            Cp[rowoff + ocol + n * 16] =
                f2b((acc[m][n][r] - mean) * inv * gv[n] + pv[n]);
        } else {
#pragma unroll
          for (int n = 0; n < 4; ++n)
            Cp[rowoff + ocol + n * 16] = f2b(acc[m][n][r]);
        }
      }
  } else {
    float bvv[4];
#pragma unroll
    for (int n = 0; n < 4; ++n) bvv[n] = bias[ocol + n * 16];
    float* Cp = (float*)C;
#pragma unroll
    for (int m = 0; m < 4; ++m)
#pragma unroll
      for (int r = 0; r < 4; ++r) {
        size_t rowoff = (size_t)(orow + m * 16 + r) * N;
#pragma unroll
        for (int n = 0; n < 4; ++n)
          Cp[rowoff + ocol + n * 16] = acc[m][n][r] + bvv[n];
      }
  }
}

// ---------- KVpart[bh][nch] = sum_{n in chunk} k[n,d]*v[n,e] (NO atomics) ----------
__global__ __launch_bounds__(256) void kv_accum(const u16* __restrict__ qkv,
                                                float* __restrict__ KVpart) {
  int nch = blockIdx.x & 15;  // 16 chunks of 256 rows
  int bh = blockIdx.x >> 4;   // 0..31
  int b = bh >> 3, h = bh & 7;
  __shared__ float ks[64][64];
  __shared__ float vs[64][64];
  int tid = threadIdx.x;
  int ty = tid >> 4, tx = tid & 15;
  int rr = tid >> 2, cc = (tid & 3) * 16;
  float acc[4][4];
#pragma unroll
  for (int i = 0; i < 4; ++i)
#pragma unroll
    for (int j = 0; j < 4; ++j) acc[i][j] = 0.f;

  for (int t = 0; t < 4; ++t) {
    int n0 = nch * 256 + t * 64;
    __syncthreads();
    size_t base = ((size_t)(b * 4096 + n0 + rr)) * 1536 + h * 64 + cc;
    const uint4* kp = reinterpret_cast<const uint4*>(&qkv[base + 512]);
    const uint4* vp = reinterpret_cast<const uint4*>(&qkv[base + 1024]);
    uint4 k0 = kp[0], k1 = kp[1];
    uint4 v0 = vp[0], v1 = vp[1];
    unpack16(k0, k1, &ks[rr][cc]);
    unpack16(v0, v1, &vs[rr][cc]);
    __syncthreads();
    for (int n = 0; n < 64; ++n) {
      float4 k4 = *reinterpret_cast<const float4*>(&ks[n][ty * 4]);
      float4 v4 = *reinterpret_cast<const float4*>(&vs[n][tx * 4]);
      float ka[4] = {k4.x, k4.y, k4.z, k4.w};
      float va[4] = {v4.x, v4.y, v4.z, v4.w};
#pragma unroll
      for (int i = 0; i < 4; ++i)
#pragma unroll
        for (int j = 0; j < 4; ++j) acc[i][j] += ka[i] * va[j];
    }
  }
  float* dst = KVpart + ((size_t)(bh * 16 + nch)) * 4096;
#pragma unroll
  for (int i = 0; i < 4; ++i) {
    float4 st = {acc[i][0], acc[i][1], acc[i][2], acc[i][3]};
    *reinterpret_cast<float4*>(&dst[(ty * 4 + i) * 64 + tx * 4]) = st;
  }
}

// ---------- KV[bh] = sum over 16 partials ----------
__global__ __launch_bounds__(256) void kv_reduce(const float* __restrict__ KVpart,
                                                 float* __restrict__ KV) {
  int bh = blockIdx.x;  // 32
  int t = threadIdx.x;
  const float4* src = reinterpret_cast<const float4*>(KVpart + (size_t)bh * 16 * 4096);
  float4* dst = reinterpret_cast<float4*>(KV + (size_t)bh * 4096);
#pragma unroll
  for (int i = 0; i < 4; ++i) {
    int idx = t + 256 * i;
    float4 s = src[idx];
#pragma unroll
    for (int c = 1; c < 16; ++c) {
      float4 v = src[c * 1024 + idx];
      s.x += v.x; s.y += v.y; s.z += v.z; s.w += v.w;
    }
    dst[idx] = s;
  }
}

// ---------- W2[b][j][h*64+d] = scale * sum_e KV[b,h,d,e] * Wo[j,h*64+e] ----------
__global__ __launch_bounds__(256) void w2_kernel(const float* __restrict__ KV,
                                                 const u16* __restrict__ wob,
                                                 u16* __restrict__ w2) {
  int bh = blockIdx.x & 31, jt = blockIdx.x >> 5;  // jt 0..7
  int b = bh >> 3, h = bh & 7;
  __shared__ float kvs[64][64];
  int t = threadIdx.x;
  {
    const float4* src = reinterpret_cast<const float4*>(KV + (size_t)bh * 4096);
    float4* dst = reinterpret_cast<float4*>(&kvs[0][0]);
#pragma unroll
    for (int i = 0; i < 4; ++i) dst[t + 256 * i] = src[t + 256 * i];
  }
  __syncthreads();
  int jloc = t & 127, dg = t >> 7;
  int j = jt * 128 + jloc;
  float wo[64];
  const u16* wr = wob + (size_t)j * 512 + h * 64;
#pragma unroll
  for (int e8 = 0; e8 < 8; ++e8) {
    uint4 pk = *reinterpret_cast<const uint4*>(wr + e8 * 8);
    u32 wds[4] = {pk.x, pk.y, pk.z, pk.w};
#pragma unroll
    for (int i = 0; i < 4; ++i) {
      wo[e8 * 8 + 2 * i]     = bf2f((u16)(wds[i] & 0xffffu));
      wo[e8 * 8 + 2 * i + 1] = bf2f((u16)(wds[i] >> 16));
    }
  }
  const float scale = 1.0f / 32768.0f;  // 1/(sqrt(64)*4096)
  u16* outp = w2 + ((size_t)b * 1024 + j) * 512 + h * 64 + dg * 32;
#pragma unroll
  for (int dd = 0; dd < 32; ++dd) {
    int d = dg * 32 + dd;
    float acc = 0.f;
    const float4* kr = reinterpret_cast<const float4*>(&kvs[d][0]);
#pragma unroll
    for (int e4 = 0; e4 < 16; ++e4) {
      float4 kv4 = kr[e4];
      acc += kv4.x * wo[e4 * 4] + kv4.y * wo[e4 * 4 + 1] +
             kv4.z * wo[e4 * 4 + 2] + kv4.w * wo[e4 * 4 + 3];
    }
    outp[dd] = f2b(acc * scale);
  }
}

// ---------- launch ----------
extern "C" void kernel_launch(void* const* d_in, const int* in_sizes, int n_in,
                              void* d_out, int out_size, void* d_ws, size_t ws_size,
                              hipStream_t stream) {
  const float* x  = (const float*)d_in[0];
  const float* Wq = (const float*)d_in[1];
  const float* gq = (const float*)d_in[2];
  const float* bq = (const float*)d_in[3];
  const float* gk = (const float*)d_in[4];
  const float* bk = (const float*)d_in[5];
  const float* Wo = (const float*)d_in[6];
  const float* bo = (const float*)d_in[7];
  float* out = (float*)d_out;

  char* p = (char*)d_ws;
  auto carve = [&](size_t bytes) {
    char* r = p;
    p += (bytes + 255) & ~(size_t)255;
    return r;
  };
  u16* xb      = (u16*)carve((size_t)16384 * 1024 * 2);
  u16* wqb     = (u16*)carve((size_t)1536 * 1024 * 2);
  u16* wob     = (u16*)carve((size_t)1024 * 512 * 2);
  u16* qkv     = (u16*)carve((size_t)16384 * 1536 * 2);
  float* KVp   = (float*)carve((size_t)32 * 16 * 4096 * 4);
  float* KVb   = (float*)carve((size_t)32 * 4096 * 4);
  u16* w2b     = (u16*)carve((size_t)4 * 1024 * 512 * 2);

  // one launch converts x, W_qkv, W_out to bf16
  cvt3<<<2048, 256, 0, stream>>>(x, xb, 4194304, Wq, wqb, 393216, Wo, wob, 131072);
  // qkv = x @ Wqkv^T  [16384,1536], fused per-head LN on q,k  (3-buffer)
  gemm_bt<0, 3><<<128 * 12, 256, 0, stream>>>(xb, wqb, qkv, gq, bq, gk, bk,
                                              nullptr, 16384, 1536, 1024, 12,
                                              1024, 0);
  // KV partials (no atomics, no memset) then reduce
  kv_accum<<<512, 256, 0, stream>>>(qkv, KVp);
  kv_reduce<<<32, 256, 0, stream>>>(KVp, KVb);
  // W2[b] = scale * KV[b] @ Wo-slices
  w2_kernel<<<256, 256, 0, stream>>>(KVb, wob, w2b);
  // out = q @ W2[b]^T + b_out  [16384,1024] fp32  (2-buffer, 4 blk/CU, 1 round)
  gemm_bt<1, 2><<<128 * 8, 256, 0, stream>>>(qkv, w2b, out, nullptr, nullptr,
                                             nullptr, nullptr, bo, 16384, 1024,
                                             512, 8, 1536, (size_t)1024 * 512);
}